// Round 3
// baseline (3097.502 us; speedup 1.0000x reference)
//
#include <hip/hip_runtime.h>
#include <hip/hip_bf16.h>

// GenericLSTM: B=64 T=2048 I=128 H=256, fp32 in/out.
// R3: gx = inputs@W_x via bf16 MFMA GEMM (f16, gate-interleaved cols
// colp=j*4+g). Recurrent: 64 WGs x 256 thr; thread j owns all 4 gates of
// H-col j; W_h int8 in ~256 VGPRs/AGPRs; h int8 in LDS double-buffer;
// per-wave broadcast via 1 ds_read_b32 + v_readlane -> sdot4.
// R3 changes vs R2: (1) raw `s_waitcnt lgkmcnt(0); s_barrier` instead of
// __syncthreads() -- avoids the compiler's vmcnt(0) drain that serialized
// the out-store ack + gx load latency into every step; (2) gx prefetch
// deepened to 4-step blocks.

#define B_ 64
#define T_ 2048
#define I_ 128
#define H_ 256
#define NC 1024  // 4 gates * H columns

typedef __attribute__((ext_vector_type(8))) short bf16x8;
typedef __attribute__((ext_vector_type(4))) float f32x4;
typedef __attribute__((ext_vector_type(4))) _Float16 f16x4;

static __device__ __forceinline__ unsigned short f2bf(float f) {
    unsigned u = __builtin_bit_cast(unsigned, f);
    u = (u + 0x7FFFu + ((u >> 16) & 1u)) >> 16;
    return (unsigned short)u;
}

static __device__ __forceinline__ int dot4(unsigned a, unsigned b, int c) {
#if __has_builtin(__builtin_amdgcn_sdot4)
    return __builtin_amdgcn_sdot4((int)a, (int)b, c, false);
#else
    int r = c;
    r += (int)(signed char)(a) * (int)(signed char)(b);
    r += (int)(signed char)(a >> 8) * (int)(signed char)(b >> 8);
    r += (int)(signed char)(a >> 16) * (int)(signed char)(b >> 16);
    r += (int)(signed char)(a >> 24) * (int)(signed char)(b >> 24);
    return r;
#endif
}

// ---------------- P1: W_h [4,256,256] f32 -> int8, per-col scale, col
// interleaved: colp = j*4 + g. wq[colp*64 + lane] packs k=4*lane..4*lane+3.
__global__ void pack_wh(const float* __restrict__ Wh, unsigned* __restrict__ wq,
                        float* __restrict__ sws) {
    int colp = blockIdx.x;             // j*4+g
    int g = colp & 3, j = colp >> 2;
    int lane = threadIdx.x;            // k = 4*lane..4*lane+3
    float v[4];
    float m = 0.f;
#pragma unroll
    for (int u = 0; u < 4; ++u) {
        int k = lane * 4 + u;
        v[u] = Wh[(g * H_ + k) * H_ + j];
        m = fmaxf(m, fabsf(v[u]));
    }
#pragma unroll
    for (int off = 32; off; off >>= 1) m = fmaxf(m, __shfl_xor(m, off));
    float mm = (m > 0.f) ? m : 1.f;
    float inv = 127.f / mm;
    unsigned pack = 0;
#pragma unroll
    for (int u = 0; u < 4; ++u) {
        int q = (int)rintf(v[u] * inv);
        q = max(-127, min(127, q));
        pack |= ((unsigned)(q & 255)) << (8 * u);
    }
    wq[colp * 64 + lane] = pack;
    if (lane == 0) sws[colp] = mm / (127.f * 127.f);  // folds h 1/127 dequant
}

// ---------------- P2: W_x [4,128,256] f32 -> bf16 MFMA B-fragments, output
// col colp = h*4 + g: Bfrag[(c16*1024 + colp)*8 + jj] = W_x[g][k][h].
__global__ void pack_wx(const float* __restrict__ Wx,
                        unsigned short* __restrict__ bxp) {
    int f = blockIdx.x * blockDim.x + threadIdx.x;  // 0..131071
    int jj = f & 7;
    int colp = (f >> 3) & 1023;
    int c16 = f >> 13;  // 0..15
    int k = (c16 >> 2) * 32 + (c16 & 3) * 8 + jj;
    int g = colp & 3, h = colp >> 2;
    bxp[f] = f2bf(Wx[(g * I_ + k) * H_ + h]);
}

// ---------------- GEMM: gx[row][colp] = sum_k inputs[row][k]*Wx[k][colp]
// rows=131072, cols=1024, K=128 single shot. f16 output.
__global__ __launch_bounds__(256) void gemm_gx(
    const float* __restrict__ A, const unsigned short* __restrict__ Bp,
    unsigned short* __restrict__ Cg) {
    __shared__ uint4 sm[4096];  // 64 KB: As=[0..2047], Bs=[2048..4095]
    int tid = threadIdx.x;
    int mt = blockIdx.x, nt = blockIdx.y;

    const float* Ab = A + (size_t)mt * 128 * I_;
    unsigned* dstA = (unsigned*)sm;
#pragma unroll
    for (int it = 0; it < 16; ++it) {
        int flat = it * 1024 + tid * 4;
        float4 a4 = *(const float4*)(Ab + flat);
        int m = flat >> 7, k0 = flat & 127;
        int c16 = k0 >> 3, j0 = k0 & 7;  // j0 in {0,4}
        unsigned lo = (unsigned)f2bf(a4.x) | ((unsigned)f2bf(a4.y) << 16);
        unsigned hi = (unsigned)f2bf(a4.z) | ((unsigned)f2bf(a4.w) << 16);
        int didx = ((c16 * 128 + m) * 16 + j0 * 2) >> 2;
        dstA[didx] = lo;
        dstA[didx + 1] = hi;
    }
    const uint4* Bq = (const uint4*)Bp;
#pragma unroll
    for (int it = 0; it < 8; ++it) {
        int chunk = it * 2 + (tid >> 7);
        int inner = tid & 127;
        sm[2048 + chunk * 128 + inner] = Bq[chunk * 1024 + nt * 128 + inner];
    }
    __syncthreads();

    int wid = tid >> 6, lane = tid & 63;
    int r = lane & 15, q = lane >> 4;
    int mw = (wid & 1) * 64, nw = (wid >> 1) * 64;
    f32x4 acc[4][4] = {};
#pragma unroll
    for (int ki = 0; ki < 4; ++ki) {
        bf16x8 af[4], bfr[4];
#pragma unroll
        for (int x = 0; x < 4; ++x) {
            af[x] = __builtin_bit_cast(bf16x8,
                                       sm[(ki * 4 + q) * 128 + mw + x * 16 + r]);
            bfr[x] = __builtin_bit_cast(
                bf16x8, sm[2048 + (ki * 4 + q) * 128 + nw + x * 16 + r]);
        }
#pragma unroll
        for (int x = 0; x < 4; ++x)
#pragma unroll
            for (int y = 0; y < 4; ++y)
                acc[x][y] = __builtin_amdgcn_mfma_f32_16x16x32_bf16(
                    af[x], bfr[y], acc[x][y], 0, 0, 0);
    }
    __syncthreads();

    _Float16* ct = (_Float16*)sm;
#pragma unroll
    for (int x = 0; x < 4; ++x)
#pragma unroll
        for (int y = 0; y < 4; ++y)
#pragma unroll
            for (int g2 = 0; g2 < 4; ++g2) {
                int row = mw + x * 16 + q * 4 + g2;
                int colc = nw + y * 16 + r;
                ct[row * 128 + colc] = (_Float16)acc[x][y][g2];
            }
    __syncthreads();
    int m = tid >> 1, half = tid & 1;
    const uint4* src = (const uint4*)sm;
    uint4* dstg =
        (uint4*)(Cg + ((size_t)(mt * 128 + m) * NC + nt * 128 + half * 64));
#pragma unroll
    for (int i = 0; i < 8; ++i) dstg[i] = src[m * 16 + half * 8 + i];
}

// ---------------- Recurrent kernel.
// Raw barrier: LDS-visibility only (no vmcnt drain). Safe because hbuf is
// double-buffered: readers of parity p and writers of parity p are always
// separated by at least one barrier.
#define BAR() asm volatile("s_waitcnt lgkmcnt(0)\n\ts_barrier" ::: "memory")

#define STEP(PAR, GV, TOFF)                                               \
    {                                                                     \
        unsigned hd = hbuf[PAR][lane];                                    \
        int a0 = 0, a1 = 0, a2 = 0, a3 = 0;                               \
        _Pragma("unroll") for (int i = 0; i < 64; ++i) {                  \
            unsigned hs = (unsigned)__builtin_amdgcn_readlane((int)hd, i);\
            a0 = dot4(hs, w0[i], a0);                                     \
            a1 = dot4(hs, w1[i], a1);                                     \
            a2 = dot4(hs, w2[i], a2);                                     \
            a3 = dot4(hs, w3[i], a3);                                     \
        }                                                                 \
        float g0 = (float)a0 * s0 + (float)GV.x + bb0;                    \
        float g1 = (float)a1 * s1 + (float)GV.y + bb1;                    \
        float g2 = (float)a2 * s2 + (float)GV.z + bb2;                    \
        float g3 = (float)a3 * s3 + (float)GV.w + bb3;                    \
        float ig = 1.f / (1.f + __expf(-g0));                             \
        float fg = 1.f / (1.f + __expf(-g1));                             \
        float gg = 2.f / (1.f + __expf(-2.f * g2)) - 1.f;                 \
        float og = 1.f / (1.f + __expf(-g3));                             \
        c = fg * c + ig * gg;                                             \
        float th = 2.f / (1.f + __expf(-2.f * c)) - 1.f;                  \
        float h = og * th;                                                \
        op[(size_t)(TOFF) * H_] = h;                                      \
        int qv = (int)rintf(h * 127.f);                                   \
        ((signed char*)hbuf[1 - (PAR)])[j] = (signed char)qv;             \
        BAR();                                                            \
    }

__global__ __launch_bounds__(256, 1) void lstm_rec(
    const unsigned short* __restrict__ gx, const uint4* __restrict__ wq4,
    const float* __restrict__ sws, const float* __restrict__ bias,
    float* __restrict__ out) {
    int b = blockIdx.x, j = threadIdx.x;
    int lane = j & 63;

    unsigned w0[64], w1[64], w2[64], w3[64];
#pragma unroll
    for (int ii = 0; ii < 16; ++ii) {
        uint4 v0 = wq4[(j * 4 + 0) * 16 + ii];
        uint4 v1 = wq4[(j * 4 + 1) * 16 + ii];
        uint4 v2 = wq4[(j * 4 + 2) * 16 + ii];
        uint4 v3 = wq4[(j * 4 + 3) * 16 + ii];
        w0[4 * ii] = v0.x; w0[4 * ii + 1] = v0.y; w0[4 * ii + 2] = v0.z; w0[4 * ii + 3] = v0.w;
        w1[4 * ii] = v1.x; w1[4 * ii + 1] = v1.y; w1[4 * ii + 2] = v1.z; w1[4 * ii + 3] = v1.w;
        w2[4 * ii] = v2.x; w2[4 * ii + 1] = v2.y; w2[4 * ii + 2] = v2.z; w2[4 * ii + 3] = v2.w;
        w3[4 * ii] = v3.x; w3[4 * ii + 1] = v3.y; w3[4 * ii + 2] = v3.z; w3[4 * ii + 3] = v3.w;
    }
    float s0 = sws[j * 4 + 0], s1 = sws[j * 4 + 1];
    float s2 = sws[j * 4 + 2], s3 = sws[j * 4 + 3];
    float bb0 = bias[0 * H_ + j], bb1 = bias[1 * H_ + j];
    float bb2 = bias[2 * H_ + j], bb3 = bias[3 * H_ + j];

    __shared__ unsigned hbuf[2][64];
    if (j < 64) hbuf[0][j] = 0u;
    __syncthreads();

    float c = 0.f;
    const _Float16* gp = (const _Float16*)gx + (size_t)b * T_ * NC + j * 4;
    float* op = out + (size_t)b * T_ * H_ + j;

    // 4-step gx prefetch pipeline (block loads; last block reads ~8KB past
    // gxbuf into the wq region -- in-bounds of ws, values unused).
    f16x4 c0 = *(const f16x4*)(gp + 0 * NC);
    f16x4 c1 = *(const f16x4*)(gp + 1 * NC);
    f16x4 c2 = *(const f16x4*)(gp + 2 * NC);
    f16x4 c3 = *(const f16x4*)(gp + 3 * NC);

    for (int t = 0; t < T_; t += 4) {
        const _Float16* np = gp + (size_t)(t + 4) * NC;
        f16x4 n0 = *(const f16x4*)(np + 0 * NC);
        f16x4 n1 = *(const f16x4*)(np + 1 * NC);
        f16x4 n2 = *(const f16x4*)(np + 2 * NC);
        f16x4 n3 = *(const f16x4*)(np + 3 * NC);
        STEP(0, c0, t + 0);
        STEP(1, c1, t + 1);
        STEP(0, c2, t + 2);
        STEP(1, c3, t + 3);
        c0 = n0; c1 = n1; c2 = n2; c3 = n3;
    }
}

extern "C" void kernel_launch(void* const* d_in, const int* in_sizes, int n_in,
                              void* d_out, int out_size, void* d_ws,
                              size_t ws_size, hipStream_t stream) {
    const float* inputs = (const float*)d_in[0];
    const float* Wx = (const float*)d_in[1];
    const float* Wh = (const float*)d_in[2];
    const float* bias = (const float*)d_in[3];
    float* out = (float*)d_out;

    char* ws = (char*)d_ws;
    unsigned short* gxbuf = (unsigned short*)ws;   // 256 MiB f16 gx
    size_t off = (size_t)B_ * T_ * NC * 2;
    unsigned* wq = (unsigned*)(ws + off);          // 256 KiB int8 W_h
    off += (size_t)NC * 64 * 4;
    float* sws = (float*)(ws + off);               // 4 KiB scales
    off += (size_t)NC * 4;
    unsigned short* bxp = (unsigned short*)(ws + off);  // 256 KiB bf16 W_x
    off += (size_t)I_ * NC * 2;

    pack_wh<<<NC, 64, 0, stream>>>(Wh, wq, sws);
    pack_wx<<<(I_ * NC) / 256, 256, 0, stream>>>(Wx, bxp);
    gemm_gx<<<dim3((B_ * T_) / 128, NC / 128), 256, 0, stream>>>(inputs, bxp,
                                                                 gxbuf);
    lstm_rec<<<B_, 256, 0, stream>>>(gxbuf, (const uint4*)wq, sws, bias, out);
}

// Round 4
// 2893.125 us; speedup vs baseline: 1.0706x; 1.0706x over previous
//
#include <hip/hip_runtime.h>
#include <hip/hip_bf16.h>

// GenericLSTM: B=64 T=2048 I=128 H=256, fp32 in/out.
// R4: gx = inputs@W_x (+bias) via bf16 MFMA GEMM, f16 out, slot-interleaved
// cols colp = j*4 + slot, slot map i->0, g->1, f->2, o->3 so the (i,g) pair
// and (f,o) pair are adjacent dwords. Recurrent: 64 WGs x 512 thr
// (2 waves/SIMD for latency hiding); lanes <32 of each wave own (i,g) of
// H-col j, lanes >=32 own (f,o) + c/h state of the same col; exchange
// ig*tanh(g) via shfl_xor(32) -- ONE barrier/step. W_h int8 in 128 VGPRs,
// h int8 in LDS double-buffer, broadcast via 1 ds_read_b32 + v_readlane.
// gx loads + h stores batched 8 steps to amortize the barrier vmcnt drain.

#define B_ 64
#define T_ 2048
#define I_ 128
#define H_ 256
#define NC 1024  // 4 gates * H columns

typedef __attribute__((ext_vector_type(8))) short bf16x8;
typedef __attribute__((ext_vector_type(4))) float f32x4;
typedef __attribute__((ext_vector_type(2))) _Float16 f16x2;

static __device__ __forceinline__ unsigned short f2bf(float f) {
    unsigned u = __builtin_bit_cast(unsigned, f);
    u = (u + 0x7FFFu + ((u >> 16) & 1u)) >> 16;
    return (unsigned short)u;
}

static __device__ __forceinline__ int dot4(unsigned a, unsigned b, int c) {
#if __has_builtin(__builtin_amdgcn_sdot4)
    return __builtin_amdgcn_sdot4((int)a, (int)b, c, false);
#else
    int r = c;
    r += (int)(signed char)(a) * (int)(signed char)(b);
    r += (int)(signed char)(a >> 8) * (int)(signed char)(b >> 8);
    r += (int)(signed char)(a >> 16) * (int)(signed char)(b >> 16);
    r += (int)(signed char)(a >> 24) * (int)(signed char)(b >> 24);
    return r;
#endif
}

// slot map (self-inverse transposition of 1,2): i(0)->0, f(1)->2, g(2)->1,
// o(3)->3. Pair 0 = {i,g} (half=0), pair 1 = {f,o} (half=1).
static __device__ __forceinline__ int slotmap(int x) {
    return ((x & 1) << 1) | (x >> 1);
}

// ---------------- P1: W_h [4,256,256] f32 -> int8, per-col scale, cols at
// colp = j*4 + slot(g). Also emits bias re-packed to biasP[colp].
__global__ void pack_wh(const float* __restrict__ Wh, const float* __restrict__ b,
                        unsigned* __restrict__ wq, float* __restrict__ sws,
                        float* __restrict__ biasP) {
    int colp = blockIdx.x;             // j*4 + slot
    int slot = colp & 3, j = colp >> 2;
    int g = slotmap(slot);
    int lane = threadIdx.x;            // k = 4*lane..4*lane+3
    float v[4];
    float m = 0.f;
#pragma unroll
    for (int u = 0; u < 4; ++u) {
        int k = lane * 4 + u;
        v[u] = Wh[(g * H_ + k) * H_ + j];
        m = fmaxf(m, fabsf(v[u]));
    }
#pragma unroll
    for (int off = 32; off; off >>= 1) m = fmaxf(m, __shfl_xor(m, off));
    float mm = (m > 0.f) ? m : 1.f;
    float inv = 127.f / mm;
    unsigned pack = 0;
#pragma unroll
    for (int u = 0; u < 4; ++u) {
        int q = (int)rintf(v[u] * inv);
        q = max(-127, min(127, q));
        pack |= ((unsigned)(q & 255)) << (8 * u);
    }
    wq[colp * 64 + lane] = pack;
    if (lane == 0) {
        sws[colp] = mm / (127.f * 127.f);  // folds h 1/127 dequant
        biasP[colp] = b[g * H_ + j];
    }
}

// ---------------- P2: W_x [4,128,256] f32 -> bf16 MFMA B-fragments, output
// col colp = h*4 + slot(g): Bfrag[(c16*1024 + colp)*8 + jj] = W_x[g][k][h].
__global__ void pack_wx(const float* __restrict__ Wx,
                        unsigned short* __restrict__ bxp) {
    int f = blockIdx.x * blockDim.x + threadIdx.x;  // 0..131071
    int jj = f & 7;
    int colp = (f >> 3) & 1023;
    int c16 = f >> 13;  // 0..15
    int k = (c16 >> 2) * 32 + (c16 & 3) * 8 + jj;
    int slot = colp & 3, h = colp >> 2;
    int g = slotmap(slot);
    bxp[f] = f2bf(Wx[(g * I_ + k) * H_ + h]);
}

// ---------------- GEMM: gx[row][colp] = sum_k inputs[row][k]*Wx[k][colp]
// + biasP[colp]. rows=131072, cols=1024, K=128 single shot. f16 output.
__global__ __launch_bounds__(256) void gemm_gx(
    const float* __restrict__ A, const unsigned short* __restrict__ Bp,
    const float* __restrict__ biasP, unsigned short* __restrict__ Cg) {
    __shared__ uint4 sm[4096];  // 64 KB: As=[0..2047], Bs=[2048..4095]
    int tid = threadIdx.x;
    int mt = blockIdx.x, nt = blockIdx.y;

    const float* Ab = A + (size_t)mt * 128 * I_;
    unsigned* dstA = (unsigned*)sm;
#pragma unroll
    for (int it = 0; it < 16; ++it) {
        int flat = it * 1024 + tid * 4;
        float4 a4 = *(const float4*)(Ab + flat);
        int m = flat >> 7, k0 = flat & 127;
        int c16 = k0 >> 3, j0 = k0 & 7;  // j0 in {0,4}
        unsigned lo = (unsigned)f2bf(a4.x) | ((unsigned)f2bf(a4.y) << 16);
        unsigned hi = (unsigned)f2bf(a4.z) | ((unsigned)f2bf(a4.w) << 16);
        int didx = ((c16 * 128 + m) * 16 + j0 * 2) >> 2;
        dstA[didx] = lo;
        dstA[didx + 1] = hi;
    }
    const uint4* Bq = (const uint4*)Bp;
#pragma unroll
    for (int it = 0; it < 8; ++it) {
        int chunk = it * 2 + (tid >> 7);
        int inner = tid & 127;
        sm[2048 + chunk * 128 + inner] = Bq[chunk * 1024 + nt * 128 + inner];
    }
    __syncthreads();

    int wid = tid >> 6, lane = tid & 63;
    int r = lane & 15, q = lane >> 4;
    int mw = (wid & 1) * 64, nw = (wid >> 1) * 64;
    f32x4 acc[4][4] = {};
#pragma unroll
    for (int ki = 0; ki < 4; ++ki) {
        bf16x8 af[4], bfr[4];
#pragma unroll
        for (int x = 0; x < 4; ++x) {
            af[x] = __builtin_bit_cast(bf16x8,
                                       sm[(ki * 4 + q) * 128 + mw + x * 16 + r]);
            bfr[x] = __builtin_bit_cast(
                bf16x8, sm[2048 + (ki * 4 + q) * 128 + nw + x * 16 + r]);
        }
#pragma unroll
        for (int x = 0; x < 4; ++x)
#pragma unroll
            for (int y = 0; y < 4; ++y)
                acc[x][y] = __builtin_amdgcn_mfma_f32_16x16x32_bf16(
                    af[x], bfr[y], acc[x][y], 0, 0, 0);
    }
    // bias: 4 distinct cols per thread (y,r)
    float bv[4];
#pragma unroll
    for (int y = 0; y < 4; ++y) bv[y] = biasP[nt * 128 + nw + y * 16 + r];
    __syncthreads();

    _Float16* ct = (_Float16*)sm;
#pragma unroll
    for (int x = 0; x < 4; ++x)
#pragma unroll
        for (int y = 0; y < 4; ++y)
#pragma unroll
            for (int g2 = 0; g2 < 4; ++g2) {
                int row = mw + x * 16 + q * 4 + g2;
                int colc = nw + y * 16 + r;
                ct[row * 128 + colc] = (_Float16)(acc[x][y][g2] + bv[y]);
            }
    __syncthreads();
    int m = tid >> 1, half = tid & 1;
    const uint4* src = (const uint4*)sm;
    uint4* dstg =
        (uint4*)(Cg + ((size_t)(mt * 128 + m) * NC + nt * 128 + half * 64));
#pragma unroll
    for (int i = 0; i < 8; ++i) dstg[i] = src[m * 16 + half * 8 + i];
}

// ---------------- Recurrent kernel: 64 WGs x 512 threads (2 waves/SIMD).
__global__ __launch_bounds__(512, 2) void lstm_rec(
    const unsigned short* __restrict__ gx, const uint4* __restrict__ wq4,
    const float* __restrict__ sws, float* __restrict__ out) {
    int b = blockIdx.x, tid = threadIdx.x;
    int w = tid >> 6, lane = tid & 63;
    int half = lane >> 5;                 // 0: gates i,g; 1: gates f,o + state
    int j = w * 32 + (lane & 31);         // H-column
    int colA = j * 4 + half * 2;          // first slot col of this thread

    unsigned wA[64], wB[64];
#pragma unroll
    for (int ii = 0; ii < 16; ++ii) {
        uint4 vA = wq4[(size_t)colA * 16 + ii];
        uint4 vB = wq4[(size_t)(colA + 1) * 16 + ii];
        wA[4 * ii] = vA.x; wA[4 * ii + 1] = vA.y; wA[4 * ii + 2] = vA.z; wA[4 * ii + 3] = vA.w;
        wB[4 * ii] = vB.x; wB[4 * ii + 1] = vB.y; wB[4 * ii + 2] = vB.z; wB[4 * ii + 3] = vB.w;
    }
    float sA = sws[colA], sB = sws[colA + 1];

    __shared__ unsigned hbuf[2][64];
    if (tid < 64) hbuf[0][tid] = 0u;
    __syncthreads();

    float c = 0.f;
    const _Float16* gp = (const _Float16*)gx + (size_t)b * T_ * NC + colA;
    float* op = out + (size_t)b * T_ * H_ + j;

    for (int tb = 0; tb < T_; tb += 8) {
        // batched gx loads for 8 steps (drained once at this step's barrier)
        f16x2 gbuf[8];
#pragma unroll
        for (int s = 0; s < 8; ++s)
            gbuf[s] = *(const f16x2*)(gp + (size_t)(tb + s) * NC);
        float hsave[8];
#pragma unroll
        for (int s = 0; s < 8; ++s) {
            int par = s & 1;
            unsigned hd = hbuf[par][lane];
            int aA = 0, aB = 0;
#pragma unroll
            for (int i = 0; i < 64; ++i) {
                unsigned hs = (unsigned)__builtin_amdgcn_readlane((int)hd, i);
                aA = dot4(hs, wA[i], aA);
                aB = dot4(hs, wB[i], aB);
            }
            float gA = (float)aA * sA + (float)gbuf[s].x;  // i or f gate
            float gB = (float)aB * sB + (float)gbuf[s].y;  // g or o gate
            float sigA = 1.f / (1.f + __expf(-gA));
            float p = 0.f;
            if (half == 0) {
                float tg = 2.f / (1.f + __expf(-2.f * gB)) - 1.f;  // tanh(g)
                p = sigA * tg;                                     // i*g
            }
            float pr = __shfl_xor(p, 32);  // half=1 receives partner's i*g
            if (half) {
                float og = 1.f / (1.f + __expf(-gB));
                c = sigA * c + pr;         // sigA = forget gate here
                float th = 2.f / (1.f + __expf(-2.f * c) ) - 1.f;
                float h = og * th;
                hsave[s] = h;
                ((signed char*)hbuf[par ^ 1])[j] = (signed char)(int)rintf(h * 127.f);
            }
            __syncthreads();
        }
        if (half) {  // batched h stores (ack drained once per 8 steps)
#pragma unroll
            for (int s = 0; s < 8; ++s) op[(size_t)(tb + s) * H_] = hsave[s];
        }
    }
}

extern "C" void kernel_launch(void* const* d_in, const int* in_sizes, int n_in,
                              void* d_out, int out_size, void* d_ws,
                              size_t ws_size, hipStream_t stream) {
    const float* inputs = (const float*)d_in[0];
    const float* Wx = (const float*)d_in[1];
    const float* Wh = (const float*)d_in[2];
    const float* bias = (const float*)d_in[3];
    float* out = (float*)d_out;

    char* ws = (char*)d_ws;
    unsigned short* gxbuf = (unsigned short*)ws;   // 256 MiB f16 gx(+bias)
    size_t off = (size_t)B_ * T_ * NC * 2;
    unsigned* wq = (unsigned*)(ws + off);          // 256 KiB int8 W_h
    off += (size_t)NC * 64 * 4;
    float* sws = (float*)(ws + off);               // 4 KiB scales
    off += (size_t)NC * 4;
    float* biasP = (float*)(ws + off);             // 4 KiB packed bias
    off += (size_t)NC * 4;
    unsigned short* bxp = (unsigned short*)(ws + off);  // 256 KiB bf16 W_x
    off += (size_t)I_ * NC * 2;

    pack_wh<<<NC, 64, 0, stream>>>(Wh, bias, wq, sws, biasP);
    pack_wx<<<(I_ * NC) / 256, 256, 0, stream>>>(Wx, bxp);
    gemm_gx<<<dim3((B_ * T_) / 128, NC / 128), 256, 0, stream>>>(inputs, bxp,
                                                                 biasP, gxbuf);
    lstm_rec<<<B_, 512, 0, stream>>>(gxbuf, (const uint4*)wq, sws, out);
}